// Round 7
// baseline (44.276 us; speedup 1.0000x reference)
//
#include <hip/hip_runtime.h>
#include <math.h>

#define NB   32
#define CIN  4
#define COUT 64
#define TT   6
#define VV   512
#define P_OFF (NB*COUT*TT*VV)   // out then p in d_out
#define SPLITS 16
#define CH   (VV/SPLITS)        // 32 softmax rows per block
#define NROW 24                 // c*6+t rows of x per batch
#define E_FLOATS (2*NB*VV)      // e_i + e_j in ws

// ---------------------------------------------------------------------------
// Kernel 1: e_i[n,v], e_j[n,v]  (collapsed xc -> x1 -> e chain)
// ---------------------------------------------------------------------------
__global__ __launch_bounds__(256) void e_kernel(
    const float* __restrict__ x,
    const float* __restrict__ conv_w,
    const float* __restrict__ conv_b,
    const float* __restrict__ l2_w,
    const float* __restrict__ l2_b,
    const float* __restrict__ l1_w,
    float* __restrict__ e)
{
    __shared__ float W1[CIN], W2[CIN], cst[2];
    int tid = threadIdx.x;
    if (tid < CIN) {
        float w1 = 0.f, w2 = 0.f;
        for (int o = 0; o < COUT; ++o) {
            w1 += l1_w[o]        * conv_w[o*CIN + tid];
            w2 += l1_w[COUT + o] * conv_w[o*CIN + tid];
        }
        W1[tid] = w1; W2[tid] = w2;
    }
    if (tid == CIN) {
        float B1 = 0.f, B2 = 0.f, S1 = 0.f, S2 = 0.f;
        for (int o = 0; o < COUT; ++o) {
            B1 += l1_w[o]        * conv_b[o];
            B2 += l1_w[COUT + o] * conv_b[o];
            S1 += l1_w[o];
            S2 += l1_w[COUT + o];
        }
        float Ls = 0.f;
        for (int t = 0; t < TT; ++t) Ls += l2_w[t];
        cst[0] = Ls*B1 + l2_b[0]*S1;
        cst[1] = Ls*B2 + l2_b[0]*S2;
    }
    __syncthreads();

    int idx = blockIdx.x * 256 + tid;      // n*V + v
    int n = idx >> 9, v = idx & (VV-1);
    float ei = cst[0], ej = cst[1];
    #pragma unroll
    for (int c = 0; c < CIN; ++c) {
        float wc1 = W1[c], wc2 = W2[c];
        #pragma unroll
        for (int t = 0; t < TT; ++t) {
            float xv = x[((n*CIN + c)*TT + t)*VV + v];
            float lw = l2_w[t];
            ei += lw*wc1*xv;
            ej += lw*wc2*xv;
        }
    }
    e[idx]         = ei;
    e[NB*VV + idx] = ej;
}

// ---------------------------------------------------------------------------
// Kernel 2 (fused): per block (s,n): 32 softmax rows -> p (global) and
// y_part[r][w] = sum_{i in chunk} x[n,r,i]*p[n,i,w].
// 256 thr = 4 waves; 4 subs of 8 rows; wave q computes rows q*2,q*2+1 per sub
// (j = lane*8+m), stages them in double-buffered LDS (1 barrier/sub), then
// accumulates its (rg = q>>1 : 12 rows, wh = q&1 : w-half) slice:
// acc[12][4] per lane, w = wh*256 + lane*4 + k (b128 p-reads/y-stores).
// 4 blocks/CU -> phase-staggered blocks hide mask-load latency.
// ---------------------------------------------------------------------------
__global__ __launch_bounds__(256, 4) void fused_kernel(
    const float* __restrict__ x,
    const int*   __restrict__ A,
    const float* __restrict__ e,
    const float* __restrict__ l1_b,
    float*       __restrict__ p,
    float*       __restrict__ ypart)
{
    __shared__ float xst[CH][2][20];     // [i][rg][rr(0..11)] 5 KB (pad->16B align)
    __shared__ float ps[2][8][VV];       // 32 KB double-buffered p stage

    int s = blockIdx.x;                  // 16 chunks of 32 rows
    int n = blockIdx.y;
    int tid = threadIdx.x;
    int lane = tid & 63;
    int q = tid >> 6;                    // wave 0..3
    int rg = q >> 1;                     // r-group (12 rows)
    int wh = q & 1;                      // w-half

    // stage x slab: xst[i][r/12][r%12], global-coalesced
    for (int l = tid; l < NROW*CH; l += 256) {
        int r = l >> 5, i = l & 31;
        xst[i][r/12][r%12] = x[((size_t)n*NROW + r)*VV + s*CH + i];
    }

    float l1b_val = l1_b[0];
    float4 ej0 = *(const float4*)(e + NB*VV + n*VV + lane*8);
    float4 ej1 = *(const float4*)(e + NB*VV + n*VV + lane*8 + 4);
    float ejv[8] = {ej0.x, ej0.y, ej0.z, ej0.w, ej1.x, ej1.y, ej1.z, ej1.w};

    const int* mbase = A + (size_t)(n*8 + 7)*VV*VV;

    float acc[12][4];
    #pragma unroll
    for (int rr = 0; rr < 12; ++rr)
        #pragma unroll
        for (int k = 0; k < 4; ++k) acc[rr][k] = 0.f;
    float a24[4] = {0.f, 0.f, 0.f, 0.f};

    // prefetch sub 0 rows for this wave (rows q*2, q*2+1)
    int iA0 = s*CH + q*2;
    int4 mA0, mA1, mB0, mB1;
    float bA, bB;
    {
        const int* mrA = mbase + (size_t)iA0*VV + lane*8;
        mA0 = *(const int4*)mrA;       mA1 = *(const int4*)(mrA + 4);
        mB0 = *(const int4*)(mrA+VV);  mB1 = *(const int4*)(mrA + VV + 4);
        bA = e[n*VV + iA0]; bB = e[n*VV + iA0 + 1];
    }
    // no barrier here: xst's first read is after sub0's barrier

    for (int sub = 0; sub < 4; ++sub) {
        int i_gA = s*CH + sub*8 + q*2;

        int4 cA0 = mA0, cA1 = mA1, cB0 = mB0, cB1 = mB1;
        float biasA = bA + l1b_val, biasB = bB + l1b_val;

        if (sub < 3) {                   // prefetch next sub's rows
            const int* mrA = mbase + (size_t)(i_gA + 8)*VV + lane*8;
            mA0 = *(const int4*)mrA;       mA1 = *(const int4*)(mrA + 4);
            mB0 = *(const int4*)(mrA+VV);  mB1 = *(const int4*)(mrA + VV + 4);
            bA = e[n*VV + i_gA + 8]; bB = e[n*VV + i_gA + 9];
        }

        // ---- softmax rows A & B (j = lane*8 + m) ----
        float svA[8], svB[8];
        int mkA[8] = {cA0.x,cA0.y,cA0.z,cA0.w, cA1.x,cA1.y,cA1.z,cA1.w};
        int mkB[8] = {cB0.x,cB0.y,cB0.z,cB0.w, cB1.x,cB1.y,cB1.z,cB1.w};
        #pragma unroll
        for (int m2 = 0; m2 < 8; ++m2) {
            float tA = biasA + ejv[m2]; tA = (tA >= 0.f) ? tA : 0.2f*tA;
            svA[m2] = (mkA[m2] == 0) ? -INFINITY : tA;
            float tB = biasB + ejv[m2]; tB = (tB >= 0.f) ? tB : 0.2f*tB;
            svB[m2] = (mkB[m2] == 0) ? -INFINITY : tB;
        }
        float mA = svA[0], mB = svB[0];
        #pragma unroll
        for (int m2 = 1; m2 < 8; ++m2) {
            mA = fmaxf(mA, svA[m2]); mB = fmaxf(mB, svB[m2]);
        }
        #pragma unroll
        for (int off = 32; off; off >>= 1) {
            mA = fmaxf(mA, __shfl_xor(mA, off));
            mB = fmaxf(mB, __shfl_xor(mB, off));
        }
        float sumA = 0.f, sumB = 0.f;
        if (mA > -INFINITY) {
            #pragma unroll
            for (int m2 = 0; m2 < 8; ++m2) { svA[m2] = __expf(svA[m2]-mA); sumA += svA[m2]; }
        } else {
            #pragma unroll
            for (int m2 = 0; m2 < 8; ++m2) svA[m2] = 0.f;
        }
        if (mB > -INFINITY) {
            #pragma unroll
            for (int m2 = 0; m2 < 8; ++m2) { svB[m2] = __expf(svB[m2]-mB); sumB += svB[m2]; }
        } else {
            #pragma unroll
            for (int m2 = 0; m2 < 8; ++m2) svB[m2] = 0.f;
        }
        #pragma unroll
        for (int off = 32; off; off >>= 1) {
            sumA += __shfl_xor(sumA, off);
            sumB += __shfl_xor(sumB, off);
        }
        float invA = (sumA > 0.f) ? 1.f/sumA : 0.f;
        float invB = (sumB > 0.f) ? 1.f/sumB : 0.f;

        float4 pA03 = {svA[0]*invA, svA[1]*invA, svA[2]*invA, svA[3]*invA};
        float4 pA47 = {svA[4]*invA, svA[5]*invA, svA[6]*invA, svA[7]*invA};
        float4 pB03 = {svB[0]*invB, svB[1]*invB, svB[2]*invB, svB[3]*invB};
        float4 pB47 = {svB[4]*invB, svB[5]*invB, svB[6]*invB, svB[7]*invB};

        // global p stores (16B/lane, coalesced)
        float* prA = p + ((size_t)(n*VV + i_gA))*VV + lane*8;
        *(float4*)prA            = pA03;
        *(float4*)(prA + 4)      = pA47;
        *(float4*)(prA + VV)     = pB03;
        *(float4*)(prA + VV + 4) = pB47;

        // LDS p-row stage (buffer sub&1)
        float* pd = &ps[sub & 1][q*2][lane*8];
        *(float4*)pd          = pA03;
        *(float4*)(pd + 4)    = pA47;
        *(float4*)(pd + VV)   = pB03;
        *(float4*)(pd + VV+4) = pB47;

        __syncthreads();   // ps[sub&1] ready (single barrier per sub)

        // ---- accumulate (rg, wh) slice: w = wh*256 + lane*4 + k ----
        const float (*psb)[VV] = ps[sub & 1];
        #pragma unroll
        for (int i = 0; i < 8; ++i) {
            float4 pv = *(const float4*)&psb[i][wh*256 + lane*4];
            const float* xr = &xst[sub*8 + i][rg][0];
            float4 xa = *(const float4*)(xr);
            float4 xb = *(const float4*)(xr + 4);
            float4 xc = *(const float4*)(xr + 8);
            float xv[12] = {xa.x,xa.y,xa.z,xa.w, xb.x,xb.y,xb.z,xb.w,
                            xc.x,xc.y,xc.z,xc.w};
            float pvk[4] = {pv.x, pv.y, pv.z, pv.w};
            #pragma unroll
            for (int rr = 0; rr < 12; ++rr)
                #pragma unroll
                for (int k = 0; k < 4; ++k)
                    acc[rr][k] = fmaf(xv[rr], pvk[k], acc[rr][k]);
            if (rg == 0) {
                #pragma unroll
                for (int k = 0; k < 4; ++k) a24[k] += pvk[k];
            }
        }
        // next sub writes the other ps buffer; this barrier fences reuse
    }

    // ---- write ypart (b128, coalesced); (rg,wh) tiles are disjoint ----
    float* yo = ypart + (size_t)(s*NB + n)*25*VV + wh*256 + lane*4;
    #pragma unroll
    for (int rr = 0; rr < 12; ++rr) {
        float4 st = {acc[rr][0], acc[rr][1], acc[rr][2], acc[rr][3]};
        *(float4*)(yo + (size_t)(rg*12 + rr)*VV) = st;
    }
    if (rg == 0) {
        float4 st = {a24[0], a24[1], a24[2], a24[3]};
        *(float4*)(yo + (size_t)24*VV) = st;
    }
}

// ---------------------------------------------------------------------------
// Kernel 3: out[n,o,t,w] = sum_c conv_w[o,c]*y[c*6+t,w] + conv_b[o]*y[24,w]
// Stages + split-reduces ypart through LDS exactly once. 512 blocks.
// ---------------------------------------------------------------------------
__global__ __launch_bounds__(256) void expand_kernel(
    const float* __restrict__ ypart,
    const float* __restrict__ conv_w,
    const float* __restrict__ conv_b,
    float*       __restrict__ out)
{
    __shared__ float ysm[25][32];
    __shared__ float wsm[COUT*CIN];
    __shared__ float bsm[COUT];

    int wc = blockIdx.x;                 // 16 w-chunks of 32
    int n  = blockIdx.y;
    int tid = threadIdx.x;

    if (tid < COUT*CIN) wsm[tid] = conv_w[tid];
    if (tid < COUT)     bsm[tid] = conv_b[tid];

    // stage + reduce splits: 25*32 = 800 floats as 200 float4
    for (int l4 = tid; l4 < 200; l4 += 256) {
        int r = l4 >> 3, w8 = l4 & 7;
        float4 a = {0.f, 0.f, 0.f, 0.f};
        #pragma unroll
        for (int s = 0; s < SPLITS; ++s) {
            float4 v = *(const float4*)(ypart +
                ((size_t)(s*NB + n)*25 + r)*VV + wc*32 + w8*4);
            a.x += v.x; a.y += v.y; a.z += v.z; a.w += v.w;
        }
        *(float4*)&ysm[r][w8*4] = a;
    }
    __syncthreads();

    int w  = tid & 31;
    int og = tid >> 5;                   // 8 groups x 8 o

    float y[25];
    #pragma unroll
    for (int r = 0; r < 25; ++r) y[r] = ysm[r][w];

    #pragma unroll
    for (int oo = 0; oo < 8; ++oo) {
        int o = og*8 + oo;
        float wb[CIN];
        #pragma unroll
        for (int c = 0; c < CIN; ++c) wb[c] = wsm[o*CIN + c];
        float bo = bsm[o];
        #pragma unroll
        for (int t = 0; t < TT; ++t) {
            float val = bo * y[24];
            #pragma unroll
            for (int c = 0; c < CIN; ++c) val = fmaf(wb[c], y[c*TT + t], val);
            out[((size_t)(n*COUT + o)*TT + t)*VV + wc*32 + w] = val;
        }
    }
}

// ---------------------------------------------------------------------------
extern "C" void kernel_launch(void* const* d_in, const int* in_sizes, int n_in,
                              void* d_out, int out_size, void* d_ws, size_t ws_size,
                              hipStream_t stream)
{
    const float* x      = (const float*)d_in[0];
    const int*   A      = (const int*)  d_in[1];
    const float* conv_w = (const float*)d_in[2];
    const float* conv_b = (const float*)d_in[3];
    const float* l2_w   = (const float*)d_in[4];
    const float* l2_b   = (const float*)d_in[5];
    const float* l1_w   = (const float*)d_in[6];
    const float* l1_b   = (const float*)d_in[7];

    float* out = (float*)d_out;
    float* pP  = out + P_OFF;              // p region of d_out
    float* e   = (float*)d_ws;             // 128 KB
    float* yp  = e + E_FLOATS;             // SPLITS*NB*25*VV f32 = 26.2 MB

    e_kernel<<<NB*VV/256, 256, 0, stream>>>(x, conv_w, conv_b, l2_w, l2_b, l1_w, e);

    dim3 gf(SPLITS, NB);                   // 512 blocks x 256 thr (4/CU)
    fused_kernel<<<gf, 256, 0, stream>>>(x, A, e, l1_b, pP, yp);

    dim3 ge(16, NB);                       // 512 blocks
    expand_kernel<<<ge, 256, 0, stream>>>(yp, conv_w, conv_b, out);
}